// Round 8
// baseline (587.115 us; speedup 1.0000x reference)
//
#include <hip/hip_runtime.h>
#include <math.h>

// Shapes fixed: B=8,h=8,H=W=64,d=32,WS=8x8 -> 64 maps, 4096 pix/map, 64 clusters.
// d_out: c_q[131072] | c_v[131072] | rpb[16777216]
// ws (floats): cq0[131072] | cen[8192] | partial[1024*4288] | rp0[262144]

#define NMAPS   64
#define LPIX    4096
#define NCLUS   64
#define DIM     32
#define CHUNKS  16          // blocks per map (256 pixels each)
#define PSTRIDE 4288        // per-block partial: 2048 q + 2048 v + 64 s + 64 ch + 64 cw

__global__ __launch_bounds__(256) void k_initcenter(const float* __restrict__ xk,
                                                    float* __restrict__ cq0) {
    int wid  = threadIdx.x >> 6;
    int lane = threadIdx.x & 63;
    int c    = blockIdx.x * 4 + wid;        // center id 0..4095
    int bh   = c >> 6, m = c & 63;
    int wh   = m >> 3, wc = m & 7;
    int d    = lane & 31, half = lane >> 5;
    const float* base = xk + (size_t)bh * LPIX * DIM;
    float s = 0.f;
#pragma unroll
    for (int k = 0; k < 32; ++k) {
        int pix = k * 2 + half;
        int r = pix >> 3, cc = pix & 7;
        int row = wh * 8 + r, col = wc * 8 + cc;
        s += base[((row << 6) + col) * DIM + d];
    }
    s += __shfl_xor(s, 32);
    float ss = s * s;
#pragma unroll
    for (int o = 16; o >= 1; o >>= 1) ss += __shfl_xor(ss, o);
    float mean = s * (1.0f / 64.0f);
    float norm = sqrtf(ss) * (1.0f / 64.0f);
    float inv  = 1.0f / fmaxf(norm, 1e-12f);
    if (half == 0) cq0[(size_t)c * DIM + d] = mean * inv;
}

// initial RPE table (map-independent): exp(-dist(pixel, analytic window center))
__global__ __launch_bounds__(256) void k_rpe0(float* __restrict__ rp0) {
    int g = blockIdx.x * 256 + threadIdx.x;   // l*64+m
    int m = g & 63, l = g >> 6;
    float fi = (float)(l >> 6);
    float fj = (float)(l & 63);
    float dh = fi - (float)((m >> 3) * 8) - 3.5f;
    float dw = fj - (float)((m & 7) * 8) - 3.5f;
    rp0[g] = expf(-sqrtf(fmaf(dh, dh, dw * dw)));
}

// Lane-owns-cluster assign: centers resident in VGPRs, pixels broadcast from LDS,
// winner-predicated register accumulation. No memory deps in the dot loop.
__global__ __launch_bounds__(256, 4) void k_assign(const float* __restrict__ xk,
                                                   const float* __restrict__ xv,
                                                   const float* __restrict__ scale,
                                                   const float* __restrict__ cq0,
                                                   const float* __restrict__ rp0,
                                                   float* __restrict__ partial) {
    __shared__ float sk_[4][256];           // per-wave stage: 8 pixels x 32 dims (k)
    __shared__ float sv_[4][256];           // same for v
    __shared__ float shq[NCLUS * 33];       // padded block accumulators
    __shared__ float shv[NCLUS * 33];
    __shared__ float shs[NCLUS], shch[NCLUS], shcw[NCLUS];

    int t    = threadIdx.x;
    int lane = t & 63;
    int wid  = t >> 6;
    int bh    = blockIdx.x >> 4;
    int chunk = blockIdx.x & (CHUNKS - 1);
    int pixbase = chunk * 256 + wid * 64;   // this wave's 64 pixels

    for (int i = t; i < NCLUS * 33; i += 256) { shq[i] = 0.f; shv[i] = 0.f; }
    if (t < NCLUS) { shs[t] = 0.f; shch[t] = 0.f; shcw[t] = 0.f; }
    __syncthreads();

    float qs = 0.17677669529663687f * scale[0];
    const float* xkb = xk + (size_t)bh * LPIX * DIM;
    const float* xvb = xv + (size_t)bh * LPIX * DIM;

    // centers for cluster m = lane, resident in registers
    float c[DIM];
    {
        const float4* cp = (const float4*)(cq0 + (size_t)bh * 2048 + lane * DIM);
#pragma unroll
        for (int g = 0; g < 8; ++g) {
            float4 c4 = cp[g];
            c[g*4] = c4.x; c[g*4+1] = c4.y; c[g*4+2] = c4.z; c[g*4+3] = c4.w;
        }
    }

    float accq[DIM], accv[DIM];
#pragma unroll
    for (int d = 0; d < DIM; ++d) { accq[d] = 0.f; accv[d] = 0.f; }
    float s = 0.f, ch = 0.f, cw = 0.f;

    for (int tile = 0; tile < 8; ++tile) {
        int tp = pixbase + tile * 8;        // 8 pixels staged per tile
        {
            float4 kk = *(const float4*)(xkb + (size_t)tp * DIM + lane * 4);
            float4 vv = *(const float4*)(xvb + (size_t)tp * DIM + lane * 4);
            *(float4*)&sk_[wid][lane * 4] = kk;
            *(float4*)&sv_[wid][lane * 4] = vv;
        }
#pragma unroll
        for (int i = 0; i < 8; ++i) {
            int l = tp + i;
            float fi = (float)(l >> 6);
            float fj = (float)(l & 63);
            float rp = rp0[(size_t)l * 64 + lane];      // coalesced, L2-resident
            // dot in exact Round-7 order (ascending k, serial fmaf chain)
            float dot = 0.f;
#pragma unroll
            for (int g = 0; g < 8; ++g) {
                float4 x4 = *(const float4*)&sk_[wid][i * 32 + g * 4];  // broadcast
                dot = fmaf(x4.x, c[g*4+0], dot);
                dot = fmaf(x4.y, c[g*4+1], dot);
                dot = fmaf(x4.z, c[g*4+2], dot);
                dot = fmaf(x4.w, c[g*4+3], dot);
            }
            float val = fmaf(dot, qs, rp);
            float mx = val;
#pragma unroll
            for (int o = 32; o >= 1; o >>= 1) mx = fmaxf(mx, __shfl_xor(mx, o));
            unsigned long long ball = __ballot(val == mx);
            float w = 1.0f / (float)__popcll(ball);
            if (val == mx) {                 // winner lanes accumulate their cluster
                s += w; ch += w * fi; cw += w * fj;
#pragma unroll
                for (int g = 0; g < 8; ++g) {
                    float4 x4 = *(const float4*)&sk_[wid][i * 32 + g * 4];
                    float4 v4 = *(const float4*)&sv_[wid][i * 32 + g * 4];
                    accq[g*4+0] = fmaf(w, x4.x, accq[g*4+0]);
                    accq[g*4+1] = fmaf(w, x4.y, accq[g*4+1]);
                    accq[g*4+2] = fmaf(w, x4.z, accq[g*4+2]);
                    accq[g*4+3] = fmaf(w, x4.w, accq[g*4+3]);
                    accv[g*4+0] = fmaf(w, v4.x, accv[g*4+0]);
                    accv[g*4+1] = fmaf(w, v4.y, accv[g*4+1]);
                    accv[g*4+2] = fmaf(w, v4.z, accv[g*4+2]);
                    accv[g*4+3] = fmaf(w, v4.w, accv[g*4+3]);
                }
            }
        }
    }

    // cross-wave combine (bank-spread via stride 33)
#pragma unroll
    for (int d = 0; d < DIM; ++d) {
        atomicAdd(&shq[lane * 33 + d], accq[d]);
        atomicAdd(&shv[lane * 33 + d], accv[d]);
    }
    atomicAdd(&shs[lane], s);
    atomicAdd(&shch[lane], ch);
    atomicAdd(&shcw[lane], cw);
    __syncthreads();

    float* pw = partial + (size_t)blockIdx.x * PSTRIDE;
    for (int i = t; i < 2048; i += 256) {
        int sidx = (i >> 5) * 33 + (i & 31);
        pw[i]        = shq[sidx];
        pw[2048 + i] = shv[sidx];
    }
    if (t < NCLUS) {
        pw[4096 + t] = shs[t];
        pw[4160 + t] = shch[t];
        pw[4224 + t] = shcw[t];
    }
}

__global__ __launch_bounds__(256) void k_reduce(const float* __restrict__ partial,
                                                float* __restrict__ out,
                                                float* __restrict__ cen) {
    __shared__ float sk[2048], sv[2048];
    __shared__ float ss_[NCLUS], sch[NCLUS], scw[NCLUS];
    __shared__ float invq[NCLUS], invv[NCLUS];
    int bh = blockIdx.x, t = threadIdx.x;
    const float* pw = partial + (size_t)bh * CHUNKS * PSTRIDE;

    for (int i = t; i < 2048; i += 256) {
        float a = 0.f, b = 0.f;
#pragma unroll
        for (int p = 0; p < CHUNKS; ++p) {
            a += pw[(size_t)p * PSTRIDE + i];
            b += pw[(size_t)p * PSTRIDE + 2048 + i];
        }
        sk[i] = a; sv[i] = b;
    }
    if (t < NCLUS) {
        float a = 0.f, b = 0.f, c = 0.f;
#pragma unroll
        for (int p = 0; p < CHUNKS; ++p) {
            a += pw[(size_t)p * PSTRIDE + 4096 + t];
            b += pw[(size_t)p * PSTRIDE + 4160 + t];
            c += pw[(size_t)p * PSTRIDE + 4224 + t];
        }
        ss_[t] = a; sch[t] = b; scw[t] = c;
    }
    __syncthreads();
    if (t < NCLUS) {
        float s2 = 0.f;
#pragma unroll
        for (int d = 0; d < DIM; ++d) { float v = sk[t * DIM + d]; s2 = fmaf(v, v, s2); }
        invq[t] = 1.0f / fmaxf(sqrtf(s2), 1e-12f);
        float s  = ss_[t];
        float sp = (s == 0.f) ? 1.f : s;
        invv[t] = 1.0f / sp;
        cen[bh * NCLUS + t]        = sch[t] / sp;
        cen[4096 + bh * NCLUS + t] = scw[t] / sp;
    }
    __syncthreads();
    float* cq = out;
    float* cv = out + 131072;
    for (int i = t; i < 2048; i += 256) {
        int m = i >> 5;
        cq[(size_t)bh * 2048 + i] = sk[i] * invq[m];
        cv[(size_t)bh * 2048 + i] = sv[i] * invv[m];
    }
}

// 4 clusters per thread, float4 store
__global__ __launch_bounds__(256) void k_rpb(const float* __restrict__ cen,
                                             float* __restrict__ out) {
    int g4 = blockIdx.x * 256 + threadIdx.x;   // 0 .. 4194303
    int mg = (g4 & 15) * 4;
    int lbh = g4 >> 4;
    int l  = lbh & 4095;
    int bh = lbh >> 12;
    float fi = (float)(l >> 6);
    float fj = (float)(l & 63);
    float4 ch4 = *(const float4*)&cen[bh * 64 + mg];
    float4 cw4 = *(const float4*)&cen[4096 + bh * 64 + mg];
    float4 o;
    { float dh = fi - ch4.x, dw = fj - cw4.x; o.x = expf(-sqrtf(fmaf(dh, dh, dw * dw))); }
    { float dh = fi - ch4.y, dw = fj - cw4.y; o.y = expf(-sqrtf(fmaf(dh, dh, dw * dw))); }
    { float dh = fi - ch4.z, dw = fj - cw4.z; o.z = expf(-sqrtf(fmaf(dh, dh, dw * dw))); }
    { float dh = fi - ch4.w, dw = fj - cw4.w; o.w = expf(-sqrtf(fmaf(dh, dh, dw * dw))); }
    *(float4*)&out[262144 + (size_t)g4 * 4] = o;
}

extern "C" void kernel_launch(void* const* d_in, const int* in_sizes, int n_in,
                              void* d_out, int out_size, void* d_ws, size_t ws_size,
                              hipStream_t stream) {
    const float* xk    = (const float*)d_in[0];
    const float* xv    = (const float*)d_in[1];
    const float* scale = (const float*)d_in[2];
    float* out = (float*)d_out;
    float* ws  = (float*)d_ws;

    float* cq0     = ws;                              // 131072 floats
    float* cen     = ws + 131072;                     // 8192 floats (ch | cw)
    float* partial = ws + 139264;                     // 1024 * 4288 floats (~17.6 MB)
    float* rp0     = ws + 139264 + 1024 * PSTRIDE;    // 262144 floats (1 MB)

    k_initcenter<<<1024, 256, 0, stream>>>(xk, cq0);
    k_rpe0<<<1024, 256, 0, stream>>>(rp0);
    k_assign<<<NMAPS * CHUNKS, 256, 0, stream>>>(xk, xv, scale, cq0, rp0, partial);
    k_reduce<<<NMAPS, 256, 0, stream>>>(partial, out, cen);
    k_rpb<<<16384, 256, 0, stream>>>(cen, out);
}

// Round 10
// 392.393 us; speedup vs baseline: 1.4962x; 1.4962x over previous
//
#include <hip/hip_runtime.h>
#include <math.h>

// Shapes fixed: B=8,h=8,H=W=64,d=32,WS=8x8 -> 64 maps, 4096 pix/map, 64 clusters.
// d_out: c_q[131072] | c_v[131072] | rpb[16777216]
// ws (floats): cq0[131072] | cen[8192] | partial[1024*4288] | rp0[262144]

#define NMAPS   64
#define LPIX    4096
#define NCLUS   64
#define DIM     32
#define CHUNKS  16          // blocks per map (256 pixels each)
#define PSTRIDE 4288        // per-block partial: 2048 q + 2048 v + 64 s + 64 ch + 64 cw

__global__ __launch_bounds__(256) void k_initcenter(const float* __restrict__ xk,
                                                    float* __restrict__ cq0) {
    int wid  = threadIdx.x >> 6;
    int lane = threadIdx.x & 63;
    int c    = blockIdx.x * 4 + wid;        // center id 0..4095
    int bh   = c >> 6, m = c & 63;
    int wh   = m >> 3, wc = m & 7;
    int d    = lane & 31, half = lane >> 5;
    const float* base = xk + (size_t)bh * LPIX * DIM;
    float s = 0.f;
#pragma unroll
    for (int k = 0; k < 32; ++k) {
        int pix = k * 2 + half;
        int r = pix >> 3, cc = pix & 7;
        int row = wh * 8 + r, col = wc * 8 + cc;
        s += base[((row << 6) + col) * DIM + d];
    }
    s += __shfl_xor(s, 32);
    float ss = s * s;
#pragma unroll
    for (int o = 16; o >= 1; o >>= 1) ss += __shfl_xor(ss, o);
    float mean = s * (1.0f / 64.0f);
    float norm = sqrtf(ss) * (1.0f / 64.0f);
    float inv  = 1.0f / fmaxf(norm, 1e-12f);
    if (half == 0) cq0[(size_t)c * DIM + d] = mean * inv;
}

// initial RPE table (map-independent): exp(-dist(pixel, analytic window center))
__global__ __launch_bounds__(256) void k_rpe0(float* __restrict__ rp0) {
    int g = blockIdx.x * 256 + threadIdx.x;   // l*64+m
    int m = g & 63, l = g >> 6;
    float fi = (float)(l >> 6);
    float fj = (float)(l & 63);
    float dh = fi - (float)((m >> 3) * 8) - 3.5f;
    float dw = fj - (float)((m & 7) * 8) - 3.5f;
    rp0[g] = expf(-sqrtf(fmaf(dh, dh, dw * dw)));
}

// Lane-owns-cluster assign: centers resident in VGPRs, pixels broadcast from LDS,
// winner-predicated register accumulation. No memory deps in the dot loop.
// NOTE: no min-waves clamp — __launch_bounds__(256,4) capped VGPRs at 64 and
// spilled all accumulators to scratch (426MB fetch + 414MB write, 4x slowdown).
__global__ __launch_bounds__(256) void k_assign(const float* __restrict__ xk,
                                                const float* __restrict__ xv,
                                                const float* __restrict__ scale,
                                                const float* __restrict__ cq0,
                                                const float* __restrict__ rp0,
                                                float* __restrict__ partial) {
    __shared__ float sk_[4][256];           // per-wave stage: 8 pixels x 32 dims (k)
    __shared__ float sv_[4][256];           // same for v
    __shared__ float shq[NCLUS * 33];       // padded block accumulators
    __shared__ float shv[NCLUS * 33];
    __shared__ float shs[NCLUS], shch[NCLUS], shcw[NCLUS];

    int t    = threadIdx.x;
    int lane = t & 63;
    int wid  = t >> 6;
    int bh    = blockIdx.x >> 4;
    int chunk = blockIdx.x & (CHUNKS - 1);
    int pixbase = chunk * 256 + wid * 64;   // this wave's 64 pixels

    for (int i = t; i < NCLUS * 33; i += 256) { shq[i] = 0.f; shv[i] = 0.f; }
    if (t < NCLUS) { shs[t] = 0.f; shch[t] = 0.f; shcw[t] = 0.f; }
    __syncthreads();

    float qs = 0.17677669529663687f * scale[0];
    const float* xkb = xk + (size_t)bh * LPIX * DIM;
    const float* xvb = xv + (size_t)bh * LPIX * DIM;

    // centers for cluster m = lane, resident in registers
    float c[DIM];
    {
        const float4* cp = (const float4*)(cq0 + (size_t)bh * 2048 + lane * DIM);
#pragma unroll
        for (int g = 0; g < 8; ++g) {
            float4 c4 = cp[g];
            c[g*4] = c4.x; c[g*4+1] = c4.y; c[g*4+2] = c4.z; c[g*4+3] = c4.w;
        }
    }

    float accq[DIM], accv[DIM];
#pragma unroll
    for (int d = 0; d < DIM; ++d) { accq[d] = 0.f; accv[d] = 0.f; }
    float s = 0.f, ch = 0.f, cw = 0.f;

    for (int tile = 0; tile < 8; ++tile) {
        int tp = pixbase + tile * 8;        // 8 pixels staged per tile
        {
            float4 kk = *(const float4*)(xkb + (size_t)tp * DIM + lane * 4);
            float4 vv = *(const float4*)(xvb + (size_t)tp * DIM + lane * 4);
            *(float4*)&sk_[wid][lane * 4] = kk;
            *(float4*)&sv_[wid][lane * 4] = vv;
        }
#pragma unroll
        for (int i = 0; i < 8; ++i) {
            int l = tp + i;
            float fi = (float)(l >> 6);
            float fj = (float)(l & 63);
            float rp = rp0[(size_t)l * 64 + lane];      // coalesced, L2-resident
            // dot in exact verified order (ascending k, serial fmaf chain)
            float dot = 0.f;
#pragma unroll
            for (int g = 0; g < 8; ++g) {
                float4 x4 = *(const float4*)&sk_[wid][i * 32 + g * 4];  // broadcast
                dot = fmaf(x4.x, c[g*4+0], dot);
                dot = fmaf(x4.y, c[g*4+1], dot);
                dot = fmaf(x4.z, c[g*4+2], dot);
                dot = fmaf(x4.w, c[g*4+3], dot);
            }
            float val = fmaf(dot, qs, rp);
            float mx = val;
#pragma unroll
            for (int o = 32; o >= 1; o >>= 1) mx = fmaxf(mx, __shfl_xor(mx, o));
            unsigned long long ball = __ballot(val == mx);
            float w = 1.0f / (float)__popcll(ball);
            float wsel = (val == mx) ? w : 0.0f;        // predicated winner weight
            s += wsel; ch += wsel * fi; cw += wsel * fj;
#pragma unroll
            for (int g = 0; g < 8; ++g) {
                float4 x4 = *(const float4*)&sk_[wid][i * 32 + g * 4];
                float4 v4 = *(const float4*)&sv_[wid][i * 32 + g * 4];
                accq[g*4+0] = fmaf(wsel, x4.x, accq[g*4+0]);
                accq[g*4+1] = fmaf(wsel, x4.y, accq[g*4+1]);
                accq[g*4+2] = fmaf(wsel, x4.z, accq[g*4+2]);
                accq[g*4+3] = fmaf(wsel, x4.w, accq[g*4+3]);
                accv[g*4+0] = fmaf(wsel, v4.x, accv[g*4+0]);
                accv[g*4+1] = fmaf(wsel, v4.y, accv[g*4+1]);
                accv[g*4+2] = fmaf(wsel, v4.z, accv[g*4+2]);
                accv[g*4+3] = fmaf(wsel, v4.w, accv[g*4+3]);
            }
        }
    }

    // cross-wave combine (bank-spread via stride 33)
#pragma unroll
    for (int d = 0; d < DIM; ++d) {
        atomicAdd(&shq[lane * 33 + d], accq[d]);
        atomicAdd(&shv[lane * 33 + d], accv[d]);
    }
    atomicAdd(&shs[lane], s);
    atomicAdd(&shch[lane], ch);
    atomicAdd(&shcw[lane], cw);
    __syncthreads();

    float* pw = partial + (size_t)blockIdx.x * PSTRIDE;
    for (int i = t; i < 2048; i += 256) {
        int sidx = (i >> 5) * 33 + (i & 31);
        pw[i]        = shq[sidx];
        pw[2048 + i] = shv[sidx];
    }
    if (t < NCLUS) {
        pw[4096 + t] = shs[t];
        pw[4160 + t] = shch[t];
        pw[4224 + t] = shcw[t];
    }
}

__global__ __launch_bounds__(256) void k_reduce(const float* __restrict__ partial,
                                                float* __restrict__ out,
                                                float* __restrict__ cen) {
    __shared__ float sk[2048], sv[2048];
    __shared__ float ss_[NCLUS], sch[NCLUS], scw[NCLUS];
    __shared__ float invq[NCLUS], invv[NCLUS];
    int bh = blockIdx.x, t = threadIdx.x;
    const float* pw = partial + (size_t)bh * CHUNKS * PSTRIDE;

    for (int i = t; i < 2048; i += 256) {
        float a = 0.f, b = 0.f;
#pragma unroll
        for (int p = 0; p < CHUNKS; ++p) {
            a += pw[(size_t)p * PSTRIDE + i];
            b += pw[(size_t)p * PSTRIDE + 2048 + i];
        }
        sk[i] = a; sv[i] = b;
    }
    if (t < NCLUS) {
        float a = 0.f, b = 0.f, c = 0.f;
#pragma unroll
        for (int p = 0; p < CHUNKS; ++p) {
            a += pw[(size_t)p * PSTRIDE + 4096 + t];
            b += pw[(size_t)p * PSTRIDE + 4160 + t];
            c += pw[(size_t)p * PSTRIDE + 4224 + t];
        }
        ss_[t] = a; sch[t] = b; scw[t] = c;
    }
    __syncthreads();
    if (t < NCLUS) {
        float s2 = 0.f;
#pragma unroll
        for (int d = 0; d < DIM; ++d) { float v = sk[t * DIM + d]; s2 = fmaf(v, v, s2); }
        invq[t] = 1.0f / fmaxf(sqrtf(s2), 1e-12f);
        float s  = ss_[t];
        float sp = (s == 0.f) ? 1.f : s;
        invv[t] = 1.0f / sp;
        cen[bh * NCLUS + t]        = sch[t] / sp;
        cen[4096 + bh * NCLUS + t] = scw[t] / sp;
    }
    __syncthreads();
    float* cq = out;
    float* cv = out + 131072;
    for (int i = t; i < 2048; i += 256) {
        int m = i >> 5;
        cq[(size_t)bh * 2048 + i] = sk[i] * invq[m];
        cv[(size_t)bh * 2048 + i] = sv[i] * invv[m];
    }
}

// 4 clusters per thread, float4 store
__global__ __launch_bounds__(256) void k_rpb(const float* __restrict__ cen,
                                             float* __restrict__ out) {
    int g4 = blockIdx.x * 256 + threadIdx.x;   // 0 .. 4194303
    int mg = (g4 & 15) * 4;
    int lbh = g4 >> 4;
    int l  = lbh & 4095;
    int bh = lbh >> 12;
    float fi = (float)(l >> 6);
    float fj = (float)(l & 63);
    float4 ch4 = *(const float4*)&cen[bh * 64 + mg];
    float4 cw4 = *(const float4*)&cen[4096 + bh * 64 + mg];
    float4 o;
    { float dh = fi - ch4.x, dw = fj - cw4.x; o.x = expf(-sqrtf(fmaf(dh, dh, dw * dw))); }
    { float dh = fi - ch4.y, dw = fj - cw4.y; o.y = expf(-sqrtf(fmaf(dh, dh, dw * dw))); }
    { float dh = fi - ch4.z, dw = fj - cw4.z; o.z = expf(-sqrtf(fmaf(dh, dh, dw * dw))); }
    { float dh = fi - ch4.w, dw = fj - cw4.w; o.w = expf(-sqrtf(fmaf(dh, dh, dw * dw))); }
    *(float4*)&out[262144 + (size_t)g4 * 4] = o;
}

extern "C" void kernel_launch(void* const* d_in, const int* in_sizes, int n_in,
                              void* d_out, int out_size, void* d_ws, size_t ws_size,
                              hipStream_t stream) {
    const float* xk    = (const float*)d_in[0];
    const float* xv    = (const float*)d_in[1];
    const float* scale = (const float*)d_in[2];
    float* out = (float*)d_out;
    float* ws  = (float*)d_ws;

    float* cq0     = ws;                              // 131072 floats
    float* cen     = ws + 131072;                     // 8192 floats (ch | cw)
    float* partial = ws + 139264;                     // 1024 * 4288 floats (~17.6 MB)
    float* rp0     = ws + 139264 + 1024 * PSTRIDE;    // 262144 floats (1 MB)

    k_initcenter<<<1024, 256, 0, stream>>>(xk, cq0);
    k_rpe0<<<1024, 256, 0, stream>>>(rp0);
    k_assign<<<NMAPS * CHUNKS, 256, 0, stream>>>(xk, xv, scale, cq0, rp0, partial);
    k_reduce<<<NMAPS, 256, 0, stream>>>(partial, out, cen);
    k_rpb<<<16384, 256, 0, stream>>>(cen, out);
}

// Round 12
// 242.731 us; speedup vs baseline: 2.4188x; 1.6166x over previous
//
#include <hip/hip_runtime.h>
#include <math.h>

// Shapes fixed: B=8,h=8,H=W=64,d=32,WS=8x8 -> 64 maps, 4096 pix/map, 64 clusters.
// d_out: c_q[131072] | c_v[131072] | rpb[16777216]
// ws (floats): cq0[131072] | cen[8192] | partial[1024*4288] | rp0[262144]

#define NMAPS   64
#define LPIX    4096
#define NCLUS   64
#define DIM     32
#define CHUNKS  16          // blocks per map, 256 pixels each, 1 pixel/thread
#define PSTRIDE 4288        // per-block partial: 2048 q + 2048 v + 64 s + 64 ch + 64 cw

// initCenter (mean-pool + L2 norm) folded with the map-independent initial-RPE
// table (window centers are analytic: (wh*8+3.5, wc*8+3.5)).
__global__ __launch_bounds__(256) void k_initcenter(const float* __restrict__ xk,
                                                    float* __restrict__ cq0,
                                                    float* __restrict__ rp0) {
    int wid  = threadIdx.x >> 6;
    int lane = threadIdx.x & 63;
    int c    = blockIdx.x * 4 + wid;        // center id 0..4095
    int bh   = c >> 6, m = c & 63;
    int wh   = m >> 3, wc = m & 7;
    int d    = lane & 31, half = lane >> 5;
    const float* base = xk + (size_t)bh * LPIX * DIM;
    float s = 0.f;
#pragma unroll
    for (int k = 0; k < 32; ++k) {
        int pix = k * 2 + half;
        int r = pix >> 3, cc = pix & 7;
        int row = wh * 8 + r, col = wc * 8 + cc;
        s += base[((row << 6) + col) * DIM + d];
    }
    s += __shfl_xor(s, 32);
    float ss = s * s;
#pragma unroll
    for (int o = 16; o >= 1; o >>= 1) ss += __shfl_xor(ss, o);
    float mean = s * (1.0f / 64.0f);
    float norm = sqrtf(ss) * (1.0f / 64.0f);
    float inv  = 1.0f / fmaxf(norm, 1e-12f);
    if (half == 0) cq0[(size_t)c * DIM + d] = mean * inv;

    // one rp0 element per thread (262144 threads total == table size)
    int g  = blockIdx.x * 256 + threadIdx.x;       // l*64+mm
    int mm = g & 63, l = g >> 6;
    float fi = (float)(l >> 6);
    float fj = (float)(l & 63);
    float dh = fi - (float)((mm >> 3) * 8) - 3.5f;
    float dw = fj - (float)((mm & 7) * 8) - 3.5f;
    rp0[g] = expf(-sqrtf(fmaf(dh, dh, dw * dw)));
}

// Thread-per-pixel assign (Round-4-verified arithmetic): centers in LDS,
// per-thread serial scan over 64 clusters (no cross-lane ops), LDS-atomic
// scatter with stride-33 padding. Grid 1024 blocks -> 4 blocks/CU resident.
__global__ __launch_bounds__(256) void k_assign(const float* __restrict__ xk,
                                                const float* __restrict__ xv,
                                                const float* __restrict__ scale,
                                                const float* __restrict__ cq0,
                                                const float* __restrict__ rp0,
                                                float* __restrict__ partial) {
    __shared__ float cs[NCLUS * DIM];       // 8 KB centers
    __shared__ float aq[NCLUS * 33];        // padded accumulators (bank-spread)
    __shared__ float av[NCLUS * 33];
    __shared__ float as_[NCLUS], ach[NCLUS], acw[NCLUS];

    int t     = threadIdx.x;
    int bh    = blockIdx.x >> 4;
    int chunk = blockIdx.x & (CHUNKS - 1);

#pragma unroll
    for (int i = 0; i < 8; ++i) cs[t + i * 256] = cq0[(size_t)bh * 2048 + t + i * 256];
    for (int i = t; i < NCLUS * 33; i += 256) { aq[i] = 0.f; av[i] = 0.f; }
    if (t < NCLUS) { as_[t] = 0.f; ach[t] = 0.f; acw[t] = 0.f; }
    __syncthreads();

    float qs = 0.17677669529663687f * scale[0];
    const float* xkb = xk + (size_t)bh * LPIX * DIM;
    const float* xvb = xv + (size_t)bh * LPIX * DIM;

    int l = chunk * 256 + t;                 // one pixel per thread
    float fi = (float)(l >> 6);
    float fj = (float)(l & 63);

    float xr[DIM];
    const float4* xp = (const float4*)(xkb + (size_t)l * DIM);
#pragma unroll
    for (int k = 0; k < 8; ++k) {
        float4 v = xp[k];
        xr[k*4] = v.x; xr[k*4+1] = v.y; xr[k*4+2] = v.z; xr[k*4+3] = v.w;
    }

    const float4* rpl = (const float4*)(rp0 + (size_t)l * 64);
    float mx = -INFINITY;
    unsigned long long msk = 0ull;
#pragma unroll
    for (int m4 = 0; m4 < 16; ++m4) {
        float4 r4 = rpl[m4];
        float rj[4] = {r4.x, r4.y, r4.z, r4.w};
#pragma unroll
        for (int j = 0; j < 4; ++j) {
            int m = m4 * 4 + j;
            const float4* cm4 = (const float4*)&cs[m * DIM];
            float dot = 0.f;
#pragma unroll
            for (int k = 0; k < 8; ++k) {
                float4 c4 = cm4[k];
                dot = fmaf(xr[k*4],   c4.x, dot);
                dot = fmaf(xr[k*4+1], c4.y, dot);
                dot = fmaf(xr[k*4+2], c4.z, dot);
                dot = fmaf(xr[k*4+3], c4.w, dot);
            }
            float val = fmaf(dot, qs, rj[j]);
            if (val > mx)       { mx = val; msk = 1ull << m; }
            else if (val == mx) { msk |= 1ull << m; }
        }
    }
    float w = 1.0f / (float)__popcll(msk);

    float vr[DIM];
    const float4* vp = (const float4*)(xvb + (size_t)l * DIM);
#pragma unroll
    for (int k = 0; k < 8; ++k) {
        float4 v = vp[k];
        vr[k*4] = v.x; vr[k*4+1] = v.y; vr[k*4+2] = v.z; vr[k*4+3] = v.w;
    }

    while (msk) {
        int m = __builtin_ctzll(msk);
        msk &= msk - 1;
        float* aqm = &aq[m * 33];
        float* avm = &av[m * 33];
#pragma unroll
        for (int d = 0; d < DIM; ++d) {
            atomicAdd(&aqm[d], w * xr[d]);
            atomicAdd(&avm[d], w * vr[d]);
        }
        atomicAdd(&as_[m], w);
        atomicAdd(&ach[m], w * fi);
        atomicAdd(&acw[m], w * fj);
    }
    __syncthreads();

    float* pw = partial + (size_t)blockIdx.x * PSTRIDE;
    for (int i = t; i < 2048; i += 256) {
        int sidx = (i >> 5) * 33 + (i & 31);
        pw[i]        = aq[sidx];
        pw[2048 + i] = av[sidx];
    }
    if (t < NCLUS) {
        pw[4096 + t] = as_[t];
        pw[4160 + t] = ach[t];
        pw[4224 + t] = acw[t];
    }
}

__global__ __launch_bounds__(256) void k_reduce(const float* __restrict__ partial,
                                                float* __restrict__ out,
                                                float* __restrict__ cen) {
    __shared__ float sk[2048], sv[2048];
    __shared__ float ss_[NCLUS], sch[NCLUS], scw[NCLUS];
    __shared__ float invq[NCLUS], invv[NCLUS];
    int bh = blockIdx.x, t = threadIdx.x;
    const float* pw = partial + (size_t)bh * CHUNKS * PSTRIDE;

    for (int i = t; i < 2048; i += 256) {
        float a = 0.f, b = 0.f;
#pragma unroll
        for (int p = 0; p < CHUNKS; ++p) {
            a += pw[(size_t)p * PSTRIDE + i];
            b += pw[(size_t)p * PSTRIDE + 2048 + i];
        }
        sk[i] = a; sv[i] = b;
    }
    if (t < NCLUS) {
        float a = 0.f, b = 0.f, c = 0.f;
#pragma unroll
        for (int p = 0; p < CHUNKS; ++p) {
            a += pw[(size_t)p * PSTRIDE + 4096 + t];
            b += pw[(size_t)p * PSTRIDE + 4160 + t];
            c += pw[(size_t)p * PSTRIDE + 4224 + t];
        }
        ss_[t] = a; sch[t] = b; scw[t] = c;
    }
    __syncthreads();
    if (t < NCLUS) {
        float s2 = 0.f;
#pragma unroll
        for (int d = 0; d < DIM; ++d) { float v = sk[t * DIM + d]; s2 = fmaf(v, v, s2); }
        invq[t] = 1.0f / fmaxf(sqrtf(s2), 1e-12f);
        float s  = ss_[t];
        float sp = (s == 0.f) ? 1.f : s;
        invv[t] = 1.0f / sp;
        cen[bh * NCLUS + t]        = sch[t] / sp;
        cen[4096 + bh * NCLUS + t] = scw[t] / sp;
    }
    __syncthreads();
    float* cq = out;
    float* cv = out + 131072;
    for (int i = t; i < 2048; i += 256) {
        int m = i >> 5;
        cq[(size_t)bh * 2048 + i] = sk[i] * invq[m];
        cv[(size_t)bh * 2048 + i] = sv[i] * invv[m];
    }
}

// 4 clusters per thread, float4 store
__global__ __launch_bounds__(256) void k_rpb(const float* __restrict__ cen,
                                             float* __restrict__ out) {
    int g4 = blockIdx.x * 256 + threadIdx.x;   // 0 .. 4194303
    int mg = (g4 & 15) * 4;
    int lbh = g4 >> 4;
    int l  = lbh & 4095;
    int bh = lbh >> 12;
    float fi = (float)(l >> 6);
    float fj = (float)(l & 63);
    float4 ch4 = *(const float4*)&cen[bh * 64 + mg];
    float4 cw4 = *(const float4*)&cen[4096 + bh * 64 + mg];
    float4 o;
    { float dh = fi - ch4.x, dw = fj - cw4.x; o.x = expf(-sqrtf(fmaf(dh, dh, dw * dw))); }
    { float dh = fi - ch4.y, dw = fj - cw4.y; o.y = expf(-sqrtf(fmaf(dh, dh, dw * dw))); }
    { float dh = fi - ch4.z, dw = fj - cw4.z; o.z = expf(-sqrtf(fmaf(dh, dh, dw * dw))); }
    { float dh = fi - ch4.w, dw = fj - cw4.w; o.w = expf(-sqrtf(fmaf(dh, dh, dw * dw))); }
    *(float4*)&out[262144 + (size_t)g4 * 4] = o;
}

extern "C" void kernel_launch(void* const* d_in, const int* in_sizes, int n_in,
                              void* d_out, int out_size, void* d_ws, size_t ws_size,
                              hipStream_t stream) {
    const float* xk    = (const float*)d_in[0];
    const float* xv    = (const float*)d_in[1];
    const float* scale = (const float*)d_in[2];
    float* out = (float*)d_out;
    float* ws  = (float*)d_ws;

    float* cq0     = ws;                              // 131072 floats
    float* cen     = ws + 131072;                     // 8192 floats (ch | cw)
    float* partial = ws + 139264;                     // 1024 * 4288 floats (~17.6 MB)
    float* rp0     = ws + 139264 + 1024 * PSTRIDE;    // 262144 floats (1 MB)

    k_initcenter<<<1024, 256, 0, stream>>>(xk, cq0, rp0);
    k_assign<<<NMAPS * CHUNKS, 256, 0, stream>>>(xk, xv, scale, cq0, rp0, partial);
    k_reduce<<<NMAPS, 256, 0, stream>>>(partial, out, cen);
    k_rpb<<<16384, 256, 0, stream>>>(cen, out);
}